// Round 10
// baseline (102.825 us; speedup 1.0000x reference)
//
#include <hip/hip_runtime.h>

typedef float f32x4 __attribute__((ext_vector_type(4)));
typedef float f32x16 __attribute__((ext_vector_type(16)));
typedef short s16x8 __attribute__((ext_vector_type(8)));
typedef short s16x4 __attribute__((ext_vector_type(4)));
typedef unsigned short u16;

#define NB 8
#define NC 64
#define NN 4096

// float -> bf16 bits, round-to-nearest-even
__device__ __forceinline__ u16 f2bf_rne(float f) {
    unsigned u = __float_as_uint(f);
    u += 0x7FFFu + ((u >> 16) & 1u);
    return (u16)(u >> 16);
}
__device__ __forceinline__ float bf2f(u16 v) {
    return __uint_as_float(((unsigned)v) << 16);
}
// pack two f32 -> one u32 of 2 bf16 (RNE), lo = first arg
__device__ __forceinline__ unsigned cvt_pk_bf16(float lo, float hi) {
    unsigned r;
    asm("v_cvt_pk_bf16_f32 %0, %1, %2" : "=v"(r) : "v"(lo), "v"(hi));
    return r;
}
// swap: a' = {a.lanes0-31, b.lanes0-31}, b' = {a.lanes32-63, b.lanes32-63}
__device__ __forceinline__ void pl32_swap(unsigned &a, unsigned &b) {
    asm("v_permlane32_swap_b32 %0, %1" : "+v"(a), "+v"(b));
}
// 2^x via the hardware transcendental unit (v_exp_f32)
__device__ __forceinline__ float exp2_hw(float x) {
    return __builtin_amdgcn_exp2f(x);
}

#define Z16 ((f32x16){0.f,0.f,0.f,0.f,0.f,0.f,0.f,0.f,0.f,0.f,0.f,0.f,0.f,0.f,0.f,0.f})

// ---------------------------------------------------------------------------
// Kernel 1 (unchanged): W' = [Wh(64); Wf(8); Wg(8)] @ x[b] via MFMA.
// Wf pre-scaled by log2(e). Qw/Gw: [B][N][16] bf16, top 8 zeroed. H written
// in PV-B-fragment order (Hf). Grid (b, n-tile) -> batch b pinned to XCD b.
// ---------------------------------------------------------------------------
__global__ __launch_bounds__(256, 4)
void precompute_qgh(const float* __restrict__ x,
                    const float* __restrict__ Wf,
                    const float* __restrict__ Wg,
                    const float* __restrict__ Wh,
                    u16* __restrict__ Qw, u16* __restrict__ Gw,
                    u16* __restrict__ Hf)
{
    const int b  = blockIdx.x;           // b fastest -> XCD = b
    const int n0 = blockIdx.y * 64;
    const int t  = threadIdx.x;
    const int wave = t >> 6, lane = t & 63, col = lane & 15, quad = lane >> 4;
    const float* xb = x + (size_t)b * NC * NN;

    __shared__ __align__(16) u16 WL[80][72];
    __shared__ __align__(16) u16 XT[64][72];

    #pragma unroll
    for (int r5 = 0; r5 < 5; r5++) {
        int v = r5 * 256 + t;
        int m = v >> 4, ks = (v & 15) << 2;
        const float* src = (m < 64) ? (Wh + m * 64 + ks)
                         : (m < 72) ? (Wf + (m - 64) * 64 + ks)
                                    : (Wg + (m - 72) * 64 + ks);
        const float scl = (m >= 64 && m < 72) ? 1.44269504088896f : 1.0f;
        f32x4 wv = *(const f32x4*)src;
        *(unsigned*)&WL[m][ks]     = (unsigned)f2bf_rne(wv[0] * scl) | ((unsigned)f2bf_rne(wv[1] * scl) << 16);
        *(unsigned*)&WL[m][ks + 2] = (unsigned)f2bf_rne(wv[2] * scl) | ((unsigned)f2bf_rne(wv[3] * scl) << 16);
    }
    #pragma unroll
    for (int r4 = 0; r4 < 4; r4++) {
        int v = r4 * 256 + t;
        int c = v >> 4, ns = (v & 15) << 2;
        f32x4 xv = *(const f32x4*)(xb + (size_t)c * NN + n0 + ns);
        #pragma unroll
        for (int e = 0; e < 4; e++) XT[ns + e][c] = f2bf_rne(xv[e]);
    }
    __syncthreads();

    const int n = n0 + wave * 16 + col;
    s16x8 bfrag[2], afrag[5][2];
    #pragma unroll
    for (int s = 0; s < 2; s++)
        bfrag[s] = *(const s16x8*)&XT[wave * 16 + col][s * 32 + quad * 8];
    #pragma unroll
    for (int mt = 0; mt < 5; mt++)
        #pragma unroll
        for (int s = 0; s < 2; s++)
            afrag[mt][s] = *(const s16x8*)&WL[mt * 16 + col][s * 32 + quad * 8];

    f32x4 d[5];
    #pragma unroll
    for (int mt = 0; mt < 5; mt++) d[mt] = (f32x4){0.f, 0.f, 0.f, 0.f};
    #pragma unroll
    for (int s = 0; s < 2; s++)
        #pragma unroll
        for (int mt = 0; mt < 5; mt++)
            d[mt] = __builtin_amdgcn_mfma_f32_16x16x32_bf16(afrag[mt][s], bfrag[s], d[mt], 0, 0, 0);

    union { s16x4 v; u16 e[4]; } pk4;
    #pragma unroll
    for (int r = 0; r < 4; r++) pk4.e[r] = f2bf_rne(d[4][r]);
    u16* qgbase = (quad < 2 ? Qw : Gw) + ((size_t)b * NN + n) * 16;
    *(s16x4*)(qgbase + (quad & 1) * 4) = pk4.v;
    if ((quad & 1) == 0) {
        s16x8 z;
        #pragma unroll
        for (int qz = 0; qz < 8; qz++) ((u16*)&z)[qz] = 0;
        *(s16x8*)(qgbase + 8) = z;
    }

    __syncthreads();
    u16 (*Hl)[72] = WL;                    // reuse WL space
    #pragma unroll
    for (int mt = 0; mt < 4; mt++)
        #pragma unroll
        for (int r = 0; r < 4; r++)
            Hl[mt * 16 + quad * 4 + r][wave * 16 + col] = f2bf_rne(d[mt][r]);
    __syncthreads();

    u16* HfB = Hf + (size_t)b * NC * NN + (size_t)blockIdx.y * 4096;
    #pragma unroll
    for (int it = 0; it < 2; it++) {
        int u = it * 256 + t;
        int s_local = u >> 7, chalf = (u >> 6) & 1, l = u & 63;
        s16x8 vv = *(const s16x8*)&Hl[chalf * 32 + (l & 31)][s_local * 16 + (l >> 5) * 8];
        *(s16x8*)(HfB + (size_t)((s_local * 2 + chalf) * 512 + l * 8)) = vv;
    }
}

// ---------------------------------------------------------------------------
// Kernel 2 v10: fused flash attention, 4 WAVES/SIMD (occupancy was the
// bottleneck: R8->R9 traffic halving was neutral; at 2 waves/SIMD the
// lock-phased waves serialize the MFMA and VALU/trans phases).
// Grid (8, 64), 512-thr blocks (8 waves), batch->XCD pinned. Wave w owns
// j-eighth w (16 chunks of 32 j) x the block's 64 i (2 Q-tiles). VGPR diet
// to fit 128 (__launch_bounds__(512,4)): single-buffer V/G reloaded in place
// after last use, one S block reused by both tiles sequentially.
// Epilogue: 8 j-partials tree-combined via 2 LDS slabs (f32x4 publish/
// absorb), gamma/l scale at final write, residual add, f32 store.
// ---------------------------------------------------------------------------
__global__ __launch_bounds__(512, 4)
void attention_fused(const u16* __restrict__ Qw, const u16* __restrict__ Gw,
                     const u16* __restrict__ Hf,
                     const float* __restrict__ x, const float* __restrict__ gamma,
                     float* __restrict__ out)
{
    const int b  = blockIdx.x;           // b fastest -> XCD = b
    const int i0 = blockIdx.y * 64;
    const int t  = threadIdx.x;
    const int wave = t >> 6, lane = t & 63, col = lane & 31, hi = lane >> 5;

    __shared__ __align__(16) float Slab[2][64][68];   // 34.8 KB
    __shared__ float Lsh[2][8][32];                   // [tile][wave][i]
    __shared__ float Sc[2][32];                       // [tile][i]

    const u16* Qb  = Qw + (size_t)b * NN * 16;
    const u16* Gb  = Gw + (size_t)b * NN * 16;
    const u16* Hfb = Hf + (size_t)b * NC * NN;
    const float g = gamma[0];

    // Two Q fragments (B-operand): B[k=hi*8+kk][n=i]; k>=8 zeros from layout
    s16x8 qf0 = *(const s16x8*)(Qb + (size_t)(i0 + col) * 16 + hi * 8);
    s16x8 qf1 = *(const s16x8*)(Qb + (size_t)(i0 + 32 + col) * 16 + hi * 8);

    f32x16 o00 = Z16, o01 = Z16, o10 = Z16, o11 = Z16;  // [tile][chalf]
    float ls0a = 0.f, ls0b = 0.f, ls1a = 0.f, ls1b = 0.f;

    const int jbase = wave * 512;        // this wave's j-eighth
    const u16* pvb = Hfb + (size_t)(jbase >> 4) * 1024 + (size_t)lane * 8;
    const u16* gb0 = Gb + (size_t)(jbase + col) * 16 + hi * 8;

    // single-buffer fragments, reloaded in place after last use per chunk.
    // overreads (chunk 16) land in the adjacent ws region (Hf->Gw->Qw) - benign.
    s16x8 ga = *(const s16x8*)(gb0);
    s16x8 v0 = *(const s16x8*)(pvb);
    s16x8 v1 = *(const s16x8*)(pvb + 512);
    s16x8 v2 = *(const s16x8*)(pvb + 1024);
    s16x8 v3 = *(const s16x8*)(pvb + 1536);

    for (int cc = 0; cc < 16; cc++) {
        // ---- tile 0 ----
        __builtin_amdgcn_s_setprio(1);
        {
            f32x16 S = __builtin_amdgcn_mfma_f32_32x32x16_bf16(ga, qf0, Z16, 0, 0, 0);
            #pragma unroll
            for (int r = 0; r < 16; r++) S[r] = exp2_hw(S[r]);
            #pragma unroll
            for (int r = 0; r < 16; r += 2) { ls0a += S[r]; ls0b += S[r + 1]; }
            #pragma unroll
            for (int s2 = 0; s2 < 2; s2++) {
                unsigned w0 = cvt_pk_bf16(S[8*s2+0], S[8*s2+1]);
                unsigned w2 = cvt_pk_bf16(S[8*s2+4], S[8*s2+5]);
                unsigned w1 = cvt_pk_bf16(S[8*s2+2], S[8*s2+3]);
                unsigned w3 = cvt_pk_bf16(S[8*s2+6], S[8*s2+7]);
                pl32_swap(w0, w2); pl32_swap(w1, w3);
                union { s16x8 v; unsigned u[4]; } p;
                p.u[0] = w0; p.u[1] = w1; p.u[2] = w2; p.u[3] = w3;
                o00 = __builtin_amdgcn_mfma_f32_32x32x16_bf16(p.v, s2 ? v2 : v0, o00, 0, 0, 0);
                o01 = __builtin_amdgcn_mfma_f32_32x32x16_bf16(p.v, s2 ? v3 : v1, o01, 0, 0, 0);
            }
        }
        // ---- tile 1 (same S regs; QK1 issued, then G reloaded in place) ----
        {
            f32x16 S = __builtin_amdgcn_mfma_f32_32x32x16_bf16(ga, qf1, Z16, 0, 0, 0);
            __builtin_amdgcn_s_setprio(0);
            ga = *(const s16x8*)(gb0 + (size_t)(cc + 1) * 512);
            __builtin_amdgcn_s_setprio(1);
            #pragma unroll
            for (int r = 0; r < 16; r++) S[r] = exp2_hw(S[r]);
            #pragma unroll
            for (int r = 0; r < 16; r += 2) { ls1a += S[r]; ls1b += S[r + 1]; }
            #pragma unroll
            for (int s2 = 0; s2 < 2; s2++) {
                unsigned w0 = cvt_pk_bf16(S[8*s2+0], S[8*s2+1]);
                unsigned w2 = cvt_pk_bf16(S[8*s2+4], S[8*s2+5]);
                unsigned w1 = cvt_pk_bf16(S[8*s2+2], S[8*s2+3]);
                unsigned w3 = cvt_pk_bf16(S[8*s2+6], S[8*s2+7]);
                pl32_swap(w0, w2); pl32_swap(w1, w3);
                union { s16x8 v; unsigned u[4]; } p;
                p.u[0] = w0; p.u[1] = w1; p.u[2] = w2; p.u[3] = w3;
                o10 = __builtin_amdgcn_mfma_f32_32x32x16_bf16(p.v, s2 ? v2 : v0, o10, 0, 0, 0);
                o11 = __builtin_amdgcn_mfma_f32_32x32x16_bf16(p.v, s2 ? v3 : v1, o11, 0, 0, 0);
            }
        }
        __builtin_amdgcn_s_setprio(0);
        // reload V in place for next chunk (covered by next QK+exp+cvt chain)
        {
            const u16* np = pvb + (size_t)(cc + 1) * 2048;
            v0 = *(const s16x8*)(np);
            v1 = *(const s16x8*)(np + 512);
            v2 = *(const s16x8*)(np + 1024);
            v3 = *(const s16x8*)(np + 1536);
        }
    }

    float lsum0 = ls0a + ls0b;
    float lsum1 = ls1a + ls1b;
    // combine hi-halves (lane i and i+32 hold disjoint j'-sets)
    {
        unsigned a = __float_as_uint(lsum0), c2 = a;
        pl32_swap(a, c2);
        lsum0 = __uint_as_float(a) + __uint_as_float(c2);
        unsigned d = __float_as_uint(lsum1), e2 = d;
        pl32_swap(d, e2);
        lsum1 = __uint_as_float(d) + __uint_as_float(e2);
    }
    if (hi == 0) { Lsh[0][wave][col] = lsum0; Lsh[1][wave][col] = lsum1; }

    // ---- epilogue: tree-combine 8 j-partials via 2 slabs ----
    // quadrant layout: Slab[s][chalf*32+col][tile*32 + 8*rb + 4*hi + e]
#define PUB(s) do {                                                        \
    _Pragma("unroll") for (int rb = 0; rb < 4; rb++) {                     \
        f32x4 wv;                                                          \
        _Pragma("unroll") for (int e = 0; e < 4; e++) wv[e] = o00[rb*4+e]; \
        *(f32x4*)&Slab[s][col][8*rb + 4*hi] = wv;                          \
        _Pragma("unroll") for (int e = 0; e < 4; e++) wv[e] = o01[rb*4+e]; \
        *(f32x4*)&Slab[s][32 + col][8*rb + 4*hi] = wv;                     \
        _Pragma("unroll") for (int e = 0; e < 4; e++) wv[e] = o10[rb*4+e]; \
        *(f32x4*)&Slab[s][col][32 + 8*rb + 4*hi] = wv;                     \
        _Pragma("unroll") for (int e = 0; e < 4; e++) wv[e] = o11[rb*4+e]; \
        *(f32x4*)&Slab[s][32 + col][32 + 8*rb + 4*hi] = wv;                \
    } } while (0)
#define ABS(s) do {                                                        \
    _Pragma("unroll") for (int rb = 0; rb < 4; rb++) {                     \
        f32x4 a0 = *(const f32x4*)&Slab[s][col][8*rb + 4*hi];              \
        f32x4 a1 = *(const f32x4*)&Slab[s][32 + col][8*rb + 4*hi];         \
        f32x4 a2 = *(const f32x4*)&Slab[s][col][32 + 8*rb + 4*hi];         \
        f32x4 a3 = *(const f32x4*)&Slab[s][32 + col][32 + 8*rb + 4*hi];    \
        _Pragma("unroll") for (int e = 0; e < 4; e++) {                    \
            o00[rb*4+e] += a0[e]; o01[rb*4+e] += a1[e];                    \
            o10[rb*4+e] += a2[e]; o11[rb*4+e] += a3[e]; }                  \
    } } while (0)

    if (wave == 1) PUB(0);
    if (wave == 5) PUB(1);
    __syncthreads();
    if (wave == 0) ABS(0);
    if (wave == 4) ABS(1);
    if (wave == 1) {                     // all Lsh visible after first sync
        Sc[hi][col] = g / (Lsh[hi][0][col] + Lsh[hi][1][col] + Lsh[hi][2][col] +
                           Lsh[hi][3][col] + Lsh[hi][4][col] + Lsh[hi][5][col] +
                           Lsh[hi][6][col] + Lsh[hi][7][col]);
    }
    __syncthreads();
    if (wave == 3) PUB(0);
    if (wave == 7) PUB(1);
    __syncthreads();
    if (wave == 2) ABS(0);
    if (wave == 6) ABS(1);
    __syncthreads();
    if (wave == 2) PUB(0);
    if (wave == 6) PUB(1);
    __syncthreads();
    if (wave == 0) ABS(0);
    if (wave == 4) ABS(1);
    __syncthreads();
    if (wave == 4) PUB(0);
    __syncthreads();
    if (wave == 0) {
        ABS(0);
        // final scaled write into slab 0
        #pragma unroll
        for (int rb = 0; rb < 4; rb++) {
            f32x4 s0 = *(const f32x4*)&Sc[0][8*rb + 4*hi];
            f32x4 s1 = *(const f32x4*)&Sc[1][8*rb + 4*hi];
            f32x4 wv;
            #pragma unroll
            for (int e = 0; e < 4; e++) wv[e] = o00[rb*4+e] * s0[e];
            *(f32x4*)&Slab[0][col][8*rb + 4*hi] = wv;
            #pragma unroll
            for (int e = 0; e < 4; e++) wv[e] = o01[rb*4+e] * s0[e];
            *(f32x4*)&Slab[0][32 + col][8*rb + 4*hi] = wv;
            #pragma unroll
            for (int e = 0; e < 4; e++) wv[e] = o10[rb*4+e] * s1[e];
            *(f32x4*)&Slab[0][col][32 + 8*rb + 4*hi] = wv;
            #pragma unroll
            for (int e = 0; e < 4; e++) wv[e] = o11[rb*4+e] * s1[e];
            *(f32x4*)&Slab[0][32 + col][32 + 8*rb + 4*hi] = wv;
        }
    }
    __syncthreads();
#undef PUB
#undef ABS

    // store: 512 threads cover 64c x 64i; residual add, f32 out
    {
        const int oc = t >> 3, q8 = t & 7;
        const int il = q8 * 8;
        f32x4 o0 = *(const f32x4*)&Slab[0][oc][il];
        f32x4 o1 = *(const f32x4*)&Slab[0][oc][il + 4];
        const float* xr = x   + ((size_t)b * NC + oc) * NN + i0 + il;
        float*    orow  = out + ((size_t)b * NC + oc) * NN + i0 + il;
        f32x4 x0 = *(const f32x4*)(xr);
        f32x4 x1 = *(const f32x4*)(xr + 4);
        *(f32x4*)(orow)     = o0 + x0;
        *(f32x4*)(orow + 4) = o1 + x1;
    }
}

extern "C" void kernel_launch(void* const* d_in, const int* in_sizes, int n_in,
                              void* d_out, int out_size, void* d_ws, size_t ws_size,
                              hipStream_t stream) {
    const float* x     = (const float*)d_in[0];
    const float* Wf    = (const float*)d_in[1];
    const float* Wg    = (const float*)d_in[2];
    const float* Wh    = (const float*)d_in[3];
    const float* gamma = (const float*)d_in[4];
    float* out = (float*)d_out;

    // layout: Hf first, then Gw, then Qw — so last-iteration prefetch
    // overreads (Hf -> Gw, Gw -> Qw) stay inside the workspace.
    u16* Hf = (u16*)d_ws;                       // [B][256 slices][2][512] frag-order
    u16* Gw = Hf + (size_t)NB * NC * NN;        // [B][N][16] (top 8 zeroed)
    u16* Qw = Gw + (size_t)NB * NN * 16;        // [B][N][16] (top 8 zeroed)

    precompute_qgh<<<dim3(NB, 64), 256, 0, stream>>>(x, Wf, Wg, Wh, Qw, Gw, Hf);
    attention_fused<<<dim3(NB, 64), 512, 0, stream>>>(Qw, Gw, Hf, x, gamma, out);
}